// Round 6
// baseline (320.116 us; speedup 1.0000x reference)
//
#include <hip/hip_runtime.h>
#include <hip/hip_bf16.h>

#define B_SZ 8
#define N_SZ 2304   // 48*48
#define D_SZ 768
#define TEMP_INV 20.0f

typedef __attribute__((ext_vector_type(4))) float f32x4;
typedef __attribute__((ext_vector_type(8))) __bf16 bf16x8;
typedef __attribute__((ext_vector_type(8))) unsigned short u16x8;

__device__ inline void gload16(const void* g, void* l) {
  __builtin_amdgcn_global_load_lds(
      (const __attribute__((address_space(1))) unsigned int*)g,
      (__attribute__((address_space(3))) unsigned int*)l,
      16, 0, 0);
}

// inline-asm ds_read_b128: opaque to LDS alias analysis (no auto vmcnt drains)
__device__ inline f32x4 dsr128(unsigned addr) {
  f32x4 d;
  asm volatile("ds_read_b128 %0, %1" : "=v"(d) : "v"(addr));
  return d;
}

__device__ inline float b2f(unsigned short h) {
  union { float f; unsigned u; } x;
  x.u = ((unsigned)h) << 16;
  return x.f;
}
__device__ inline unsigned short f2b(float f) {
  __hip_bfloat16 t = __float2bfloat16(f);
  return *reinterpret_cast<unsigned short*>(&t);
}

// ---------------- normalize: xn = x / max(||x||,1e-12), stored bf16 ----------
__global__ __launch_bounds__(256) void normalize_k(
    const float* __restrict__ f, __hip_bfloat16* __restrict__ xn) {
  const int row = blockIdx.x;
  const int t = threadIdx.x;
  const float* r = f + (size_t)row * D_SZ;
  float v0 = r[t], v1 = r[t + 256], v2 = r[t + 512];
  float s = v0 * v0 + v1 * v1 + v2 * v2;
#pragma unroll
  for (int m = 32; m >= 1; m >>= 1) s += __shfl_xor(s, m);
  __shared__ float red[4];
  const int wid = t >> 6, lane = t & 63;
  if (lane == 0) red[wid] = s;
  __syncthreads();
  s = red[0] + red[1] + red[2] + red[3];
  const float inv = rsqrtf(fmaxf(s, 1e-24f));
  __hip_bfloat16* o = xn + (size_t)row * D_SZ;
  o[t]       = __float2bfloat16(v0 * inv);
  o[t + 256] = __float2bfloat16(v1 * inv);
  o[t + 512] = __float2bfloat16(v2 * inv);
}

// ---------------- transpose: xt[b][d][n] = (bf16) x[b][n][d] -----------------
__global__ __launch_bounds__(256) void transpose_k(
    const float* __restrict__ f, __hip_bfloat16* __restrict__ xt) {
  __shared__ float tile[32][33];
  const int b = blockIdx.z;
  const int n0 = blockIdx.x * 32, d0 = blockIdx.y * 32;
  const int tx = threadIdx.x & 31, ty = threadIdx.x >> 5;  // 32 x 8
  const float* fb = f + (size_t)b * N_SZ * D_SZ;
#pragma unroll
  for (int j = 0; j < 4; ++j)
    tile[ty * 4 + j][tx] = fb[(size_t)(n0 + ty * 4 + j) * D_SZ + d0 + tx];
  __syncthreads();
  __hip_bfloat16* ob = xt + (size_t)b * D_SZ * N_SZ;
#pragma unroll
  for (int j = 0; j < 4; ++j)
    ob[(size_t)(d0 + ty * 4 + j) * N_SZ + n0 + tx] =
        __float2bfloat16(tile[tx][ty * 4 + j]);
}

// --------- row softmax, 8 rows/block, 32 lanes/row, bf16x8 IO, no LDS --------
__global__ __launch_bounds__(256) void softmax_k(__hip_bfloat16* corr) {
  const int t = threadIdx.x;
  const int sub = t & 31;
  const size_t row = (size_t)blockIdx.x * 8 + (t >> 5);
  unsigned short* p = (unsigned short*)(corr + row * N_SZ);
  u16x8 q[9];
  float v[72];
  float mx = -1e30f;
#pragma unroll
  for (int j = 0; j < 9; ++j) {
    q[j] = *(const u16x8*)&p[(sub + 32 * j) * 8];
#pragma unroll
    for (int e = 0; e < 8; ++e) {
      v[j * 8 + e] = b2f(q[j][e]) * TEMP_INV;
      mx = fmaxf(mx, v[j * 8 + e]);
    }
  }
#pragma unroll
  for (int m = 16; m >= 1; m >>= 1) mx = fmaxf(mx, __shfl_xor(mx, m, 32));
  float sum = 0.f;
#pragma unroll
  for (int i = 0; i < 72; ++i) {
    v[i] = __expf(v[i] - mx);
    sum += v[i];
  }
#pragma unroll
  for (int m = 16; m >= 1; m >>= 1) sum += __shfl_xor(sum, m, 32);
  const float inv = 1.0f / sum;
#pragma unroll
  for (int j = 0; j < 9; ++j) {
    u16x8 o;
#pragma unroll
    for (int e = 0; e < 8; ++e) o[e] = f2b(v[j * 8 + e] * inv);
    *(u16x8*)&p[(sub + 32 * j) * 8] = o;
  }
}

// ======= 256x256 8-wave bf16 MFMA GEMM, read-ahead software pipeline =========
// LDS ring: 4 slots x 32KB (slot = 32 k-cols: A[256][32]+B[256][32]).
// Per phase p: stage(u=p+6); lgkm(0) [reads(p) done]; odd p: counted vmcnt
// gating next half; barrier; issue reads(p+1) into reg bank (p+1)&1 (A) /
// half-parity bank (B); MFMA(p) from bank p&1 — LDS drain of reads(p+1)
// overlaps MFMA(p). One barrier per phase.
template <int MODE>
__global__ __launch_bounds__(512, 2) void gemm8_k(
    const __hip_bfloat16* __restrict__ A, const __hip_bfloat16* __restrict__ Bm,
    __hip_bfloat16* __restrict__ Cbf, const float* __restrict__ Fin,
    float* __restrict__ Fout, const int K, const int lda, const int ldb,
    const long long batchA, const long long batchB, const int ldc,
    const long long batchC, const int gx, const int gy, const int cpx) {
  __shared__ __align__(16) short lds[65536];  // 128 KB
  const int o = blockIdx.x + gx * (blockIdx.y + gy * blockIdx.z);
  const int l = (o & 7) * cpx + (o >> 3);
  const int bx = l % gx;
  const int byz = l / gx;
  const int by = byz % gy;
  const int b = byz / gy;

  const int tid = threadIdx.x;
  const int wid = tid >> 6, lane = tid & 63;
  const int wr = wid >> 2, wc = wid & 3;     // 2 x 4 wave grid
  const int fr = lane & 15, fk = lane >> 4;

  const short* Ab = (const short*)A + (size_t)b * batchA + (size_t)bx * 256 * lda;
  const short* Bb = (const short*)Bm + (size_t)b * batchB + (size_t)by * 256 * ldb;

  // staging: thread -> (row r0, LDS granule tid&3) <- global granule ^ s(r0)
  const int r0 = tid >> 2;
  const int gsw = ((tid & 3) ^ ((r0 >> 1) & 3)) * 8;
  const short* sa0 = Ab + (size_t)r0 * lda + gsw;
  const short* sa1 = Ab + (size_t)(r0 + 128) * lda + gsw;
  const short* sb0 = Bb + (size_t)r0 * ldb + gsw;
  const short* sb1 = Bb + (size_t)(r0 + 128) * ldb + gsw;
  const int dstT = tid * 8;  // shorts within 8KB L-region

  const unsigned ldsBase = (unsigned)(unsigned long long)&lds[0];
  const int g2b = (fk ^ ((fr >> 1) & 3)) * 16;  // swizzled granule, bytes
  unsigned aOffB[8], bOffB[4];
#pragma unroll
  for (int mi = 0; mi < 8; ++mi)
    aOffB[mi] = (unsigned)((wr * 128 + mi * 16 + fr) * 64 + g2b);
#pragma unroll
  for (int ni = 0; ni < 4; ++ni)
    bOffB[ni] = (unsigned)(16384 + (wc * 64 + ni * 16 + fr) * 64 + g2b);

  f32x4 acc[8][4];
#pragma unroll
  for (int i = 0; i < 8; ++i)
#pragma unroll
    for (int j = 0; j < 4; ++j) acc[i][j] = (f32x4)0.f;

  const int T = K >> 6;
  const int UMAX = 4 * T;  // unit u: half h=u>>1 (32 k-cols), part u&1 (A / B)
  const int PMAX = 4 * T;

  auto stage = [&](int u) {
    const int kOff = (u >> 1) * 32;
    short* d = &lds[((u >> 1) & 3) * 16384 + (u & 1) * 8192 + dstT];
    if (u & 1) {
      gload16(sb0 + kOff, d);
      gload16(sb1 + kOff, d + 4096);
    } else {
      gload16(sa0 + kOff, d);
      gload16(sa1 + kOff, d + 4096);
    }
  };

#pragma unroll
  for (int u = 0; u < 6; ++u) stage(u);
  asm volatile("s_waitcnt vmcnt(8)");  // halves 0,1 in flight allowance: 2,2 units
  __builtin_amdgcn_s_barrier();

  f32x4 af[2][4], bq[2][4];
  // reads for phase 0 (half 0, A rows 0-3, B all) into banks 0
#pragma unroll
  for (int ni = 0; ni < 4; ++ni) bq[0][ni] = dsr128(ldsBase + bOffB[ni]);
#pragma unroll
  for (int i = 0; i < 4; ++i) af[0][i] = dsr128(ldsBase + aOffB[i]);

  for (int t = 0; t < T; ++t) {
#pragma unroll
    for (int q = 0; q < 4; ++q) {
      const int p = 4 * t + q;
      const int u = p + 6;
      if (u < UMAX) stage(u);
      asm volatile("s_waitcnt lgkmcnt(0)");  // reads(p) complete
      __builtin_amdgcn_sched_barrier(0);
      if (q & 1) {
        // gate staging of next half (units <= p+2 must have landed)
        if (p <= PMAX - 7) {
          asm volatile("s_waitcnt vmcnt(8)");
        } else if (p == PMAX - 5) {
          asm volatile("s_waitcnt vmcnt(4)");
        } else {  // p == PMAX - 3
          asm volatile("s_waitcnt vmcnt(0)");
        }
      }
      __builtin_amdgcn_s_barrier();
      __builtin_amdgcn_sched_barrier(0);
      // issue reads for phase p+1; drain overlaps MFMA(p)
      if (p < PMAX - 1) {
        const int hn = 2 * t + ((q + 1) >> 1);
        const unsigned slotB = ldsBase + (unsigned)((hn & 3) * 32768);
        if (q & 1) {  // next phase is even: new K-half -> new B set
#pragma unroll
          for (int ni = 0; ni < 4; ++ni)
            bq[((q + 1) >> 1) & 1][ni] = dsr128(slotB + bOffB[ni]);
        }
#pragma unroll
        for (int i = 0; i < 4; ++i)
          af[(q + 1) & 1][i] = dsr128(slotB + aOffB[((q + 1) & 1) * 4 + i]);
      }
      __builtin_amdgcn_sched_barrier(0);
      __builtin_amdgcn_s_setprio(1);
#pragma unroll
      for (int i = 0; i < 4; ++i)
#pragma unroll
        for (int ni = 0; ni < 4; ++ni)
          acc[(q & 1) * 4 + i][ni] = __builtin_amdgcn_mfma_f32_16x16x32_bf16(
              __builtin_bit_cast(bf16x8, af[q & 1][i]),
              __builtin_bit_cast(bf16x8, bq[(q >> 1) & 1][ni]),
              acc[(q & 1) * 4 + i][ni], 0, 0, 0);
      __builtin_amdgcn_s_setprio(0);
    }
  }

  // epilogue. C/D layout: col = lane&15, row = (lane>>4)*4 + r
  const int row0 = bx * 256 + wr * 128 + fk * 4;
  const int col0 = by * 256 + wc * 64 + fr;
  if (MODE == 0) {
    __hip_bfloat16* Cb = Cbf + (size_t)b * batchC;
#pragma unroll
    for (int mi = 0; mi < 8; ++mi)
#pragma unroll
      for (int ni = 0; ni < 4; ++ni)
#pragma unroll
        for (int r = 0; r < 4; ++r)
          Cb[(size_t)(row0 + mi * 16 + r) * ldc + (col0 + ni * 16)] =
              __float2bfloat16(acc[mi][ni][r]);
  } else {
    const size_t base = (size_t)b * batchC;
#pragma unroll
    for (int mi = 0; mi < 8; ++mi)
#pragma unroll
      for (int ni = 0; ni < 4; ++ni)
#pragma unroll
        for (int r = 0; r < 4; ++r) {
          const size_t idx =
              base + (size_t)(row0 + mi * 16 + r) * ldc + (col0 + ni * 16);
          Fout[idx] = 0.5f * Fin[idx] + 0.5f * acc[mi][ni][r];
        }
  }
}

extern "C" void kernel_launch(void* const* d_in, const int* in_sizes, int n_in,
                              void* d_out, int out_size, void* d_ws,
                              size_t ws_size, hipStream_t stream) {
  const float* feat = (const float*)d_in[0];
  float* out = (float*)d_out;
  char* ws = (char*)d_ws;
  const size_t ND = (size_t)B_SZ * N_SZ * D_SZ;  // 14,155,776
  __hip_bfloat16* xn = (__hip_bfloat16*)ws;               // 28.3 MB
  __hip_bfloat16* xt = (__hip_bfloat16*)(ws + ND * 2);    // 28.3 MB
  __hip_bfloat16* corr = (__hip_bfloat16*)(ws + ND * 4);  // 84.9 MB

  normalize_k<<<B_SZ * N_SZ, 256, 0, stream>>>(feat, xn);
  transpose_k<<<dim3(N_SZ / 32, D_SZ / 32, B_SZ), 256, 0, stream>>>(feat, xt);
  // GEMM1: corr = xn . xn^T   grid 9x9x8 = 648 blocks
  gemm8_k<0><<<dim3(9, 9, 8), 512, 0, stream>>>(
      xn, xn, corr, nullptr, nullptr, D_SZ, D_SZ, D_SZ,
      (long long)N_SZ * D_SZ, (long long)N_SZ * D_SZ, N_SZ,
      (long long)N_SZ * N_SZ, 9, 9, 81);
  softmax_k<<<B_SZ * N_SZ / 8, 256, 0, stream>>>(corr);
  // GEMM2: out = .5*feat + .5*(W . xt^T)  grid 9x3x8 = 216 blocks
  gemm8_k<1><<<dim3(9, 3, 8), 512, 0, stream>>>(
      corr, xt, nullptr, feat, out, N_SZ, N_SZ, N_SZ,
      (long long)N_SZ * N_SZ, (long long)D_SZ * N_SZ, D_SZ,
      (long long)N_SZ * D_SZ, 9, 3, 27);
}

// Round 11
// 285.583 us; speedup vs baseline: 1.1209x; 1.1209x over previous
//
#include <hip/hip_runtime.h>
#include <hip/hip_bf16.h>

#define B_SZ 8
#define N_SZ 2304   // 48*48
#define D_SZ 768
#define TEMP_INV 20.0f

typedef __attribute__((ext_vector_type(4))) float f32x4;
typedef __attribute__((ext_vector_type(8))) __bf16 bf16x8;
typedef __attribute__((ext_vector_type(8))) unsigned short u16x8;

__device__ inline void gload16(const void* g, void* l) {
  __builtin_amdgcn_global_load_lds(
      (const __attribute__((address_space(1))) unsigned int*)g,
      (__attribute__((address_space(3))) unsigned int*)l,
      16, 0, 0);
}

// inline-asm ds_read_b128: opaque to LDS alias analysis (no auto vmcnt drains)
__device__ inline f32x4 dsr128(unsigned addr) {
  f32x4 d;
  asm volatile("ds_read_b128 %0, %1" : "=v"(d) : "v"(addr));
  return d;
}

__device__ inline float b2f(unsigned short h) {
  union { float f; unsigned u; } x;
  x.u = ((unsigned)h) << 16;
  return x.f;
}
__device__ inline unsigned short f2b(float f) {
  __hip_bfloat16 t = __float2bfloat16(f);
  return *reinterpret_cast<unsigned short*>(&t);
}

// ---------------- normalize: xn = x / max(||x||,1e-12), stored bf16 ----------
__global__ __launch_bounds__(256) void normalize_k(
    const float* __restrict__ f, __hip_bfloat16* __restrict__ xn) {
  const int row = blockIdx.x;
  const int t = threadIdx.x;
  const float* r = f + (size_t)row * D_SZ;
  float v0 = r[t], v1 = r[t + 256], v2 = r[t + 512];
  float s = v0 * v0 + v1 * v1 + v2 * v2;
#pragma unroll
  for (int m = 32; m >= 1; m >>= 1) s += __shfl_xor(s, m);
  __shared__ float red[4];
  const int wid = t >> 6, lane = t & 63;
  if (lane == 0) red[wid] = s;
  __syncthreads();
  s = red[0] + red[1] + red[2] + red[3];
  const float inv = rsqrtf(fmaxf(s, 1e-24f));
  __hip_bfloat16* o = xn + (size_t)row * D_SZ;
  o[t]       = __float2bfloat16(v0 * inv);
  o[t + 256] = __float2bfloat16(v1 * inv);
  o[t + 512] = __float2bfloat16(v2 * inv);
}

// ---------------- transpose: xt[b][d][n] = (bf16) x[b][n][d] -----------------
__global__ __launch_bounds__(256) void transpose_k(
    const float* __restrict__ f, __hip_bfloat16* __restrict__ xt) {
  __shared__ float tile[32][33];
  const int b = blockIdx.z;
  const int n0 = blockIdx.x * 32, d0 = blockIdx.y * 32;
  const int tx = threadIdx.x & 31, ty = threadIdx.x >> 5;  // 32 x 8
  const float* fb = f + (size_t)b * N_SZ * D_SZ;
#pragma unroll
  for (int j = 0; j < 4; ++j)
    tile[ty * 4 + j][tx] = fb[(size_t)(n0 + ty * 4 + j) * D_SZ + d0 + tx];
  __syncthreads();
  __hip_bfloat16* ob = xt + (size_t)b * D_SZ * N_SZ;
#pragma unroll
  for (int j = 0; j < 4; ++j)
    ob[(size_t)(d0 + ty * 4 + j) * N_SZ + n0 + tx] =
        __float2bfloat16(tile[tx][ty * 4 + j]);
}

// ====== 256x256 bf16 MFMA GEMM, merged phases (2 per K-tile of 64) ===========
// LDS ring: 4 slots x 32KB (slot = K-half, 32 k-cols: A[256][32]+B[256][32]).
// Phase p consumes half p (slot p&3): 12 ds_read_b128 (8 A-frags + 4 B-frags),
// stage half p+3 (4 gload_lds), barrier, lgkm(0), 32 MFMA, counted vmcnt
// (8 / 4@P-3 / 0@P-2), barrier.  Swizzle (measured 0 conflicts): granule
// g' = g ^ ((row>>1)&3), applied on stage source AND read address.
// MODE 0: P = exp(20*(A.B^T) - 20) bf16 + per-row partial sums -> atomicAdd.
// MODE 1: Fout = 0.5*Fin + 0.5*(A.B^T)/rowsum[row].
template <int MODE>
__global__ __launch_bounds__(512, 2) void gemm8_k(
    const __hip_bfloat16* __restrict__ A, const __hip_bfloat16* __restrict__ Bm,
    __hip_bfloat16* __restrict__ Cbf, const float* __restrict__ Fin,
    float* __restrict__ Fout, float* __restrict__ rowsum, const int K,
    const int lda, const int ldb, const long long batchA, const long long batchB,
    const int ldc, const long long batchC, const int gx, const int gy,
    const int cpx) {
  __shared__ __align__(16) short lds[65536];  // 128 KB
  const int o = blockIdx.x + gx * (blockIdx.y + gy * blockIdx.z);
  const int l = (o & 7) * cpx + (o >> 3);
  const int bx = l % gx;
  const int byz = l / gx;
  const int by = byz % gy;
  const int b = byz / gy;

  const int tid = threadIdx.x;
  const int wid = tid >> 6, lane = tid & 63;
  const int wr = wid >> 2, wc = wid & 3;     // 2 x 4 wave grid
  const int fr = lane & 15, fk = lane >> 4;

  const short* Ab = (const short*)A + (size_t)b * batchA + (size_t)bx * 256 * lda;
  const short* Bb = (const short*)Bm + (size_t)b * batchB + (size_t)by * 256 * ldb;

  // staging: thread -> (row r0, LDS granule tid&3) <- global granule ^ s(r0)
  const int r0 = tid >> 2;
  const int gsw = ((tid & 3) ^ ((r0 >> 1) & 3)) * 8;
  const short* sa0 = Ab + (size_t)r0 * lda + gsw;
  const short* sa1 = Ab + (size_t)(r0 + 128) * lda + gsw;
  const short* sb0 = Bb + (size_t)r0 * ldb + gsw;
  const short* sb1 = Bb + (size_t)(r0 + 128) * ldb + gsw;
  const int dstT = tid * 8;  // shorts within 8KB L-region

  const unsigned ldsBase = (unsigned)(unsigned long long)&lds[0];
  const int g2b = (fk ^ ((fr >> 1) & 3)) * 16;  // swizzled granule, bytes
  unsigned aOffB[8], bOffB[4];
#pragma unroll
  for (int mi = 0; mi < 8; ++mi)
    aOffB[mi] = (unsigned)((wr * 128 + mi * 16 + fr) * 64 + g2b);
#pragma unroll
  for (int ni = 0; ni < 4; ++ni)
    bOffB[ni] = (unsigned)(16384 + (wc * 64 + ni * 16 + fr) * 64 + g2b);

  f32x4 acc[8][4];
#pragma unroll
  for (int i = 0; i < 8; ++i)
#pragma unroll
    for (int j = 0; j < 4; ++j) acc[i][j] = (f32x4)0.f;

  const int T = K >> 6;
  const int P = 2 * T;  // phases; phase p = K-half p (32 k-cols)

  auto stage = [&](int u) {  // unit u: half u>>1, part u&1 (A / B)
    const int kOff = (u >> 1) * 32;
    short* d = &lds[((u >> 1) & 3) * 16384 + (u & 1) * 8192 + dstT];
    if (u & 1) {
      gload16(sb0 + kOff, d);
      gload16(sb1 + kOff, d + 4096);
    } else {
      gload16(sa0 + kOff, d);
      gload16(sa1 + kOff, d + 4096);
    }
  };

  // prologue: halves 0,1,2 (units 0..5 = 12 loads); wait half 0 landed
#pragma unroll
  for (int u = 0; u < 6; ++u) stage(u);
  asm volatile("s_waitcnt vmcnt(8)");
  __builtin_amdgcn_s_barrier();

  f32x4 af[8], bq[4];
  for (int p = 0; p < P; ++p) {
    const unsigned slotB = ldsBase + (unsigned)((p & 3) * 32768);
#pragma unroll
    for (int ni = 0; ni < 4; ++ni) bq[ni] = dsr128(slotB + bOffB[ni]);
#pragma unroll
    for (int i = 0; i < 8; ++i) af[i] = dsr128(slotB + aOffB[i]);
    if (p + 3 < P) {
      stage(2 * (p + 3));
      stage(2 * (p + 3) + 1);
    }
    __builtin_amdgcn_s_barrier();
    asm volatile("s_waitcnt lgkmcnt(0)");
    __builtin_amdgcn_sched_barrier(0);
    __builtin_amdgcn_s_setprio(1);
#pragma unroll
    for (int i = 0; i < 8; ++i)
#pragma unroll
      for (int ni = 0; ni < 4; ++ni)
        acc[i][ni] = __builtin_amdgcn_mfma_f32_16x16x32_bf16(
            __builtin_bit_cast(bf16x8, af[i]), __builtin_bit_cast(bf16x8, bq[ni]),
            acc[i][ni], 0, 0, 0);
    __builtin_amdgcn_s_setprio(0);
    if (p < P - 3) {
      asm volatile("s_waitcnt vmcnt(8)");  // half p+1 landed; never 0 mid-loop
    } else if (p == P - 3) {
      asm volatile("s_waitcnt vmcnt(4)");
    } else if (p == P - 2) {
      asm volatile("s_waitcnt vmcnt(0)");
    }
    __builtin_amdgcn_s_barrier();
  }

  // epilogue. C/D layout: col = lane&15, row = (lane>>4)*4 + r
  const int row0 = bx * 256 + wr * 128 + fk * 4;
  const int col0 = by * 256 + wc * 64 + fr;
  if (MODE == 0) {
    unsigned short* Cb = (unsigned short*)(Cbf + (size_t)b * batchC);
    float* rsb = rowsum + (size_t)b * N_SZ;
#pragma unroll
    for (int mi = 0; mi < 8; ++mi)
#pragma unroll
      for (int r = 0; r < 4; ++r) {
        float psum = 0.f;
#pragma unroll
        for (int ni = 0; ni < 4; ++ni) {
          const float e = __expf(fmaf(20.f, acc[mi][ni][r], -20.f));
          const unsigned short h = f2b(e);
          Cb[(size_t)(row0 + mi * 16 + r) * ldc + (col0 + ni * 16)] = h;
          psum += b2f(h);  // sum the ROUNDED value (matches what GEMM2 reads)
        }
#pragma unroll
        for (int m = 1; m <= 8; m <<= 1) psum += __shfl_xor(psum, m, 16);
        if (fr == 0) atomicAdd(&rsb[row0 + mi * 16 + r], psum);
      }
  } else {
    const size_t base = (size_t)b * batchC;
    const float* rsb = rowsum + (size_t)b * N_SZ;
#pragma unroll
    for (int mi = 0; mi < 8; ++mi)
#pragma unroll
      for (int r = 0; r < 4; ++r) {
        const float inv = 1.0f / rsb[row0 + mi * 16 + r];
#pragma unroll
        for (int ni = 0; ni < 4; ++ni) {
          const size_t idx =
              base + (size_t)(row0 + mi * 16 + r) * ldc + (col0 + ni * 16);
          Fout[idx] = 0.5f * Fin[idx] + 0.5f * acc[mi][ni][r] * inv;
        }
      }
  }
}

extern "C" void kernel_launch(void* const* d_in, const int* in_sizes, int n_in,
                              void* d_out, int out_size, void* d_ws,
                              size_t ws_size, hipStream_t stream) {
  const float* feat = (const float*)d_in[0];
  float* out = (float*)d_out;
  char* ws = (char*)d_ws;
  const size_t ND = (size_t)B_SZ * N_SZ * D_SZ;  // 14,155,776
  __hip_bfloat16* xn = (__hip_bfloat16*)ws;               // 28.3 MB
  __hip_bfloat16* xt = (__hip_bfloat16*)(ws + ND * 2);    // 28.3 MB
  __hip_bfloat16* corr = (__hip_bfloat16*)(ws + ND * 4);  // 84.9 MB (P = exp)
  float* rowsum = (float*)(ws + ND * 4 + (size_t)B_SZ * N_SZ * N_SZ * 2);

  hipMemsetAsync(rowsum, 0, (size_t)B_SZ * N_SZ * 4, stream);
  normalize_k<<<B_SZ * N_SZ, 256, 0, stream>>>(feat, xn);
  transpose_k<<<dim3(N_SZ / 32, D_SZ / 32, B_SZ), 256, 0, stream>>>(feat, xt);
  // GEMM1: P = exp(20*xn.xn^T - 20) + rowsums   grid 9x9x8 = 648 blocks
  gemm8_k<0><<<dim3(9, 9, 8), 512, 0, stream>>>(
      xn, xn, corr, nullptr, nullptr, rowsum, D_SZ, D_SZ, D_SZ,
      (long long)N_SZ * D_SZ, (long long)N_SZ * D_SZ, N_SZ,
      (long long)N_SZ * N_SZ, 9, 9, 81);
  // GEMM2: out = .5*feat + .5*(P . xt^T)/rowsum   grid 9x3x8 = 216 blocks
  gemm8_k<1><<<dim3(9, 3, 8), 512, 0, stream>>>(
      corr, xt, nullptr, feat, out, rowsum, N_SZ, N_SZ, N_SZ,
      (long long)N_SZ * N_SZ, (long long)D_SZ * N_SZ, D_SZ,
      (long long)N_SZ * D_SZ, 9, 3, 27);
}

// Round 12
// 283.188 us; speedup vs baseline: 1.1304x; 1.0085x over previous
//
#include <hip/hip_runtime.h>
#include <hip/hip_bf16.h>

#define B_SZ 8
#define N_SZ 2304   // 48*48
#define D_SZ 768
#define TEMP_INV 20.0f

typedef __attribute__((ext_vector_type(4))) float f32x4;
typedef __attribute__((ext_vector_type(8))) __bf16 bf16x8;
typedef __attribute__((ext_vector_type(8))) unsigned short u16x8;

__device__ inline void gload16(const void* g, void* l) {
  __builtin_amdgcn_global_load_lds(
      (const __attribute__((address_space(1))) unsigned int*)g,
      (__attribute__((address_space(3))) unsigned int*)l,
      16, 0, 0);
}

// inline-asm ds_read_b128: opaque to LDS alias analysis (no auto vmcnt drains)
__device__ inline f32x4 dsr128(unsigned addr) {
  f32x4 d;
  asm volatile("ds_read_b128 %0, %1" : "=v"(d) : "v"(addr));
  return d;
}

__device__ inline float b2f(unsigned short h) {
  union { float f; unsigned u; } x;
  x.u = ((unsigned)h) << 16;
  return x.f;
}
__device__ inline unsigned short f2b(float f) {
  __hip_bfloat16 t = __float2bfloat16(f);
  return *reinterpret_cast<unsigned short*>(&t);
}

// ---------------- normalize: xn = x / max(||x||,1e-12), stored bf16 ----------
__global__ __launch_bounds__(256) void normalize_k(
    const float* __restrict__ f, __hip_bfloat16* __restrict__ xn) {
  const int row = blockIdx.x;
  const int t = threadIdx.x;
  const float* r = f + (size_t)row * D_SZ;
  float v0 = r[t], v1 = r[t + 256], v2 = r[t + 512];
  float s = v0 * v0 + v1 * v1 + v2 * v2;
#pragma unroll
  for (int m = 32; m >= 1; m >>= 1) s += __shfl_xor(s, m);
  __shared__ float red[4];
  const int wid = t >> 6, lane = t & 63;
  if (lane == 0) red[wid] = s;
  __syncthreads();
  s = red[0] + red[1] + red[2] + red[3];
  const float inv = rsqrtf(fmaxf(s, 1e-24f));
  __hip_bfloat16* o = xn + (size_t)row * D_SZ;
  o[t]       = __float2bfloat16(v0 * inv);
  o[t + 256] = __float2bfloat16(v1 * inv);
  o[t + 512] = __float2bfloat16(v2 * inv);
}

// ---------------- transpose: xt[b][d][n] = (bf16) x[b][n][d] -----------------
__global__ __launch_bounds__(256) void transpose_k(
    const float* __restrict__ f, __hip_bfloat16* __restrict__ xt) {
  __shared__ float tile[32][33];
  const int b = blockIdx.z;
  const int n0 = blockIdx.x * 32, d0 = blockIdx.y * 32;
  const int tx = threadIdx.x & 31, ty = threadIdx.x >> 5;  // 32 x 8
  const float* fb = f + (size_t)b * N_SZ * D_SZ;
#pragma unroll
  for (int j = 0; j < 4; ++j)
    tile[ty * 4 + j][tx] = fb[(size_t)(n0 + ty * 4 + j) * D_SZ + d0 + tx];
  __syncthreads();
  __hip_bfloat16* ob = xt + (size_t)b * D_SZ * N_SZ;
#pragma unroll
  for (int j = 0; j < 4; ++j)
    ob[(size_t)(d0 + ty * 4 + j) * N_SZ + n0 + tx] =
        __float2bfloat16(tile[tx][ty * 4 + j]);
}

// ====== 256x256 bf16 MFMA GEMM, merged phases + partial-lgkm interleave ======
// LDS ring: 4 slots x 32KB (slot = K-half, 32 k-cols: A[256][32]+B[256][32]).
// Phase p: issue 12 ds_read_b128 in consumption order (bq0-3, af0-7), stage
// half p+3 (4 gload_lds), barrier, then 8 MFMA groups each gated by
// s_waitcnt lgkmcnt(7-i)+sched_barrier(0) (DS retires in order, so group i's
// af[i] is ready after 5+i retirements) -> MFMA overlaps the LDS drain.
// Counted vmcnt (8 / 4@P-3 / 0@P-2) at phase end; never 0 mid-loop.
// MODE 0: P = exp(20*(A.B^T) - 20) bf16 + per-row partial sums -> atomicAdd.
// MODE 1: Fout = 0.5*Fin + 0.5*(A.B^T)/rowsum[row].
#define MG(i, cnt)                                                        \
  asm volatile("s_waitcnt lgkmcnt(" #cnt ")");                            \
  __builtin_amdgcn_sched_barrier(0);                                      \
  _Pragma("unroll")                                                       \
  for (int ni = 0; ni < 4; ++ni)                                          \
    acc[i][ni] = __builtin_amdgcn_mfma_f32_16x16x32_bf16(                 \
        __builtin_bit_cast(bf16x8, af[i]),                                \
        __builtin_bit_cast(bf16x8, bq[ni]), acc[i][ni], 0, 0, 0);

template <int MODE>
__global__ __launch_bounds__(512, 2) void gemm8_k(
    const __hip_bfloat16* __restrict__ A, const __hip_bfloat16* __restrict__ Bm,
    __hip_bfloat16* __restrict__ Cbf, const float* __restrict__ Fin,
    float* __restrict__ Fout, float* __restrict__ rowsum, const int K,
    const int lda, const int ldb, const long long batchA, const long long batchB,
    const int ldc, const long long batchC, const int gx, const int gy,
    const int cpx) {
  __shared__ __align__(16) short lds[65536];  // 128 KB
  const int o = blockIdx.x + gx * (blockIdx.y + gy * blockIdx.z);
  const int l = (o & 7) * cpx + (o >> 3);
  const int bx = l % gx;
  const int byz = l / gx;
  const int by = byz % gy;
  const int b = byz / gy;

  const int tid = threadIdx.x;
  const int wid = tid >> 6, lane = tid & 63;
  const int wr = wid >> 2, wc = wid & 3;     // 2 x 4 wave grid
  const int fr = lane & 15, fk = lane >> 4;

  const short* Ab = (const short*)A + (size_t)b * batchA + (size_t)bx * 256 * lda;
  const short* Bb = (const short*)Bm + (size_t)b * batchB + (size_t)by * 256 * ldb;

  // staging: thread -> (row r0, LDS granule tid&3) <- global granule ^ s(r0)
  const int r0 = tid >> 2;
  const int gsw = ((tid & 3) ^ ((r0 >> 1) & 3)) * 8;
  const short* sa0 = Ab + (size_t)r0 * lda + gsw;
  const short* sa1 = Ab + (size_t)(r0 + 128) * lda + gsw;
  const short* sb0 = Bb + (size_t)r0 * ldb + gsw;
  const short* sb1 = Bb + (size_t)(r0 + 128) * ldb + gsw;
  const int dstT = tid * 8;  // shorts within 8KB L-region

  const unsigned ldsBase = (unsigned)(unsigned long long)&lds[0];
  const int g2b = (fk ^ ((fr >> 1) & 3)) * 16;  // swizzled granule, bytes
  unsigned aOffB[8], bOffB[4];
#pragma unroll
  for (int mi = 0; mi < 8; ++mi)
    aOffB[mi] = (unsigned)((wr * 128 + mi * 16 + fr) * 64 + g2b);
#pragma unroll
  for (int ni = 0; ni < 4; ++ni)
    bOffB[ni] = (unsigned)(16384 + (wc * 64 + ni * 16 + fr) * 64 + g2b);

  f32x4 acc[8][4];
#pragma unroll
  for (int i = 0; i < 8; ++i)
#pragma unroll
    for (int j = 0; j < 4; ++j) acc[i][j] = (f32x4)0.f;

  const int T = K >> 6;
  const int P = 2 * T;  // phases; phase p = K-half p (32 k-cols)

  auto stage = [&](int u) {  // unit u: half u>>1, part u&1 (A / B)
    const int kOff = (u >> 1) * 32;
    short* d = &lds[((u >> 1) & 3) * 16384 + (u & 1) * 8192 + dstT];
    if (u & 1) {
      gload16(sb0 + kOff, d);
      gload16(sb1 + kOff, d + 4096);
    } else {
      gload16(sa0 + kOff, d);
      gload16(sa1 + kOff, d + 4096);
    }
  };

  // prologue: halves 0,1,2 (units 0..5 = 12 loads); wait half 0 landed
#pragma unroll
  for (int u = 0; u < 6; ++u) stage(u);
  asm volatile("s_waitcnt vmcnt(8)");
  __builtin_amdgcn_s_barrier();

  f32x4 af[8], bq[4];
  for (int p = 0; p < P; ++p) {
    const unsigned slotB = ldsBase + (unsigned)((p & 3) * 32768);
    // issue in consumption order: B frags first, then A frags
#pragma unroll
    for (int ni = 0; ni < 4; ++ni) bq[ni] = dsr128(slotB + bOffB[ni]);
#pragma unroll
    for (int i = 0; i < 8; ++i) af[i] = dsr128(slotB + aOffB[i]);
    if (p + 3 < P) {
      stage(2 * (p + 3));
      stage(2 * (p + 3) + 1);
    }
    __builtin_amdgcn_s_barrier();
    __builtin_amdgcn_s_setprio(1);
    MG(0, 7) MG(1, 6) MG(2, 5) MG(3, 4)
    MG(4, 3) MG(5, 2) MG(6, 1) MG(7, 0)
    __builtin_amdgcn_s_setprio(0);
    if (p < P - 3) {
      asm volatile("s_waitcnt vmcnt(8)");  // half p+1 landed; never 0 mid-loop
    } else if (p == P - 3) {
      asm volatile("s_waitcnt vmcnt(4)");
    } else if (p == P - 2) {
      asm volatile("s_waitcnt vmcnt(0)");
    }
    __builtin_amdgcn_s_barrier();
  }

  // epilogue. C/D layout: col = lane&15, row = (lane>>4)*4 + r
  const int row0 = bx * 256 + wr * 128 + fk * 4;
  const int col0 = by * 256 + wc * 64 + fr;
  if (MODE == 0) {
    unsigned short* Cb = (unsigned short*)(Cbf + (size_t)b * batchC);
    float* rsb = rowsum + (size_t)b * N_SZ;
#pragma unroll
    for (int mi = 0; mi < 8; ++mi)
#pragma unroll
      for (int r = 0; r < 4; ++r) {
        float psum = 0.f;
#pragma unroll
        for (int ni = 0; ni < 4; ++ni) {
          const float e = __expf(fmaf(20.f, acc[mi][ni][r], -20.f));
          const unsigned short h = f2b(e);
          Cb[(size_t)(row0 + mi * 16 + r) * ldc + (col0 + ni * 16)] = h;
          psum += b2f(h);  // sum the ROUNDED value (matches what GEMM2 reads)
        }
#pragma unroll
        for (int m = 1; m <= 8; m <<= 1) psum += __shfl_xor(psum, m, 16);
        if (fr == 0) atomicAdd(&rsb[row0 + mi * 16 + r], psum);
      }
  } else {
    const size_t base = (size_t)b * batchC;
    const float* rsb = rowsum + (size_t)b * N_SZ;
#pragma unroll
    for (int mi = 0; mi < 8; ++mi)
#pragma unroll
      for (int r = 0; r < 4; ++r) {
        const float inv = 1.0f / rsb[row0 + mi * 16 + r];
#pragma unroll
        for (int ni = 0; ni < 4; ++ni) {
          const size_t idx =
              base + (size_t)(row0 + mi * 16 + r) * ldc + (col0 + ni * 16);
          Fout[idx] = 0.5f * Fin[idx] + 0.5f * acc[mi][ni][r] * inv;
        }
      }
  }
}

extern "C" void kernel_launch(void* const* d_in, const int* in_sizes, int n_in,
                              void* d_out, int out_size, void* d_ws,
                              size_t ws_size, hipStream_t stream) {
  const float* feat = (const float*)d_in[0];
  float* out = (float*)d_out;
  char* ws = (char*)d_ws;
  const size_t ND = (size_t)B_SZ * N_SZ * D_SZ;  // 14,155,776
  __hip_bfloat16* xn = (__hip_bfloat16*)ws;               // 28.3 MB
  __hip_bfloat16* xt = (__hip_bfloat16*)(ws + ND * 2);    // 28.3 MB
  __hip_bfloat16* corr = (__hip_bfloat16*)(ws + ND * 4);  // 84.9 MB (P = exp)
  float* rowsum = (float*)(ws + ND * 4 + (size_t)B_SZ * N_SZ * N_SZ * 2);

  hipMemsetAsync(rowsum, 0, (size_t)B_SZ * N_SZ * 4, stream);
  normalize_k<<<B_SZ * N_SZ, 256, 0, stream>>>(feat, xn);
  transpose_k<<<dim3(N_SZ / 32, D_SZ / 32, B_SZ), 256, 0, stream>>>(feat, xt);
  // GEMM1: P = exp(20*xn.xn^T - 20) + rowsums   grid 9x9x8 = 648 blocks
  gemm8_k<0><<<dim3(9, 9, 8), 512, 0, stream>>>(
      xn, xn, corr, nullptr, nullptr, rowsum, D_SZ, D_SZ, D_SZ,
      (long long)N_SZ * D_SZ, (long long)N_SZ * D_SZ, N_SZ,
      (long long)N_SZ * N_SZ, 9, 9, 81);
  // GEMM2: out = .5*feat + .5*(P . xt^T)/rowsum   grid 9x3x8 = 216 blocks
  gemm8_k<1><<<dim3(9, 3, 8), 512, 0, stream>>>(
      corr, xt, nullptr, feat, out, rowsum, N_SZ, N_SZ, N_SZ,
      (long long)N_SZ * N_SZ, (long long)D_SZ * N_SZ, D_SZ,
      (long long)N_SZ * D_SZ, 9, 3, 27);
}